// Round 5
// baseline (6419.298 us; speedup 1.0000x reference)
//
#include <hip/hip_runtime.h>
#include <stdint.h>

// ---------------------------------------------------------------------------
// GAFD_ABCD pipeline on MI355X.  R8: k_conv occupancy rebuild — BK=32,
// 64 KiB LDS double-buffer -> 2 blocks/CU (4 waves/SIMD).  Simple 1-deep
// ledger (stage T+1 during T, vmcnt(0)+barrier publish per tile), 2 prio
// phases x 16 MFMA per K32-tile, new 64B-row swizzle (slot = c ^ ((r>>1)&3)).
// wt re-laid to [ts 288][co 512][k 32].  k_ln + k_ln_s_pos fused (ftn/fsn
// round-trip eliminated).  Everything else unchanged from R7.
// ---------------------------------------------------------------------------

typedef float f32x4 __attribute__((ext_vector_type(4)));
typedef short s16x8 __attribute__((ext_vector_type(8)));

__device__ __forceinline__ unsigned short f2bf(float f) {
  unsigned u = __float_as_uint(f);
  u += 0x7fffu + ((u >> 16) & 1u);   // RNE
  return (unsigned short)(u >> 16);
}
__device__ __forceinline__ float bf2f(unsigned short h) {
  return __uint_as_float((unsigned)h << 16);
}

__device__ __forceinline__ void gld16(const void* g, void* l) {
  __builtin_amdgcn_global_load_lds(
      (const __attribute__((address_space(1))) void*)g,
      (__attribute__((address_space(3))) void*)l, 16, 0, 0);
}

__device__ __forceinline__ float block_sum(float v, float* l4) {
  for (int m = 32; m; m >>= 1) v += __shfl_xor(v, m, 64);
  int wid = threadIdx.x >> 6;
  if ((threadIdx.x & 63) == 0) l4[wid] = v;
  __syncthreads();
  float r = l4[0] + l4[1] + l4[2] + l4[3];
  __syncthreads();
  return r;
}

// ---------------- K0: fused pad-transpose + weight prep --------------------
// blocks 0..16383: teacher pad-transpose.  16384..16895: conv wprep.
// 16896..17919: t_w transpose.  17920..18431: s_w transpose.
__global__ void k_pad_wprep(const float* __restrict__ teacher,
                            unsigned short* __restrict__ tpad,
                            const float* __restrict__ w1,
                            unsigned short* __restrict__ wt,
                            const float* __restrict__ tw, unsigned short* __restrict__ wTt,
                            const float* __restrict__ sw, unsigned short* __restrict__ wTs) {
  __shared__ __align__(16) char smem[36864];
  int blk = blockIdx.x, t = threadIdx.x;
  if (blk < 16384) {
    unsigned short* lds = (unsigned short*)smem;  // 64*65 shorts
    int cb = blk & 15, y = (blk >> 4) & 63, b = blk >> 10;
#pragma unroll
    for (int it = 0; it < 4; ++it) {
      int idx = it * 256 + t;            // 1024 float4 items
      int cl = idx >> 4, x4 = (idx & 15) * 4;
      float4 v = *(const float4*)&teacher[(size_t)(b * 1024 + cb * 64 + cl) * 4096 + y * 64 + x4];
      lds[cl * 65 + x4 + 0] = f2bf(v.x);
      lds[cl * 65 + x4 + 1] = f2bf(v.y);
      lds[cl * 65 + x4 + 2] = f2bf(v.z);
      lds[cl * 65 + x4 + 3] = f2bf(v.w);
    }
    __syncthreads();
    size_t obase = ((size_t)(b * 66 + y + 1) * 66 + 1) * 1024 + cb * 64;
#pragma unroll
    for (int it = 0; it < 2; ++it) {
      int wi = it * 256 + t;             // 512 items: 64 x * 8 chunk-groups
      int x = wi >> 3, c0 = (wi & 7) * 8;
      s16x8 v;
#pragma unroll
      for (int k2 = 0; k2 < 8; ++k2) v[k2] = (short)lds[(c0 + k2) * 65 + x];
      *(s16x8*)(void*)&tpad[obase + (size_t)x * 1024 + c0] = v;
    }
    if (y == 0) {
      for (int idx = t; idx < 66 * 64; idx += 256) {
        int col = idx >> 6, cl = idx & 63;
        tpad[((size_t)(b * 66) * 66 + col) * 1024 + cb * 64 + cl] = 0;
      }
    }
    if (y == 63) {
      for (int idx = t; idx < 66 * 64; idx += 256) {
        int col = idx >> 6, cl = idx & 63;
        tpad[((size_t)(b * 66 + 65) * 66 + col) * 1024 + cb * 64 + cl] = 0;
      }
    }
    if (t < 128) {
      int col = (t >= 64) ? 65 : 0;
      int cl = t & 63;
      tpad[((size_t)(b * 66 + y + 1) * 66 + col) * 1024 + cb * 64 + cl] = 0;
    }
  } else if (blk < 16896) {
    float* wl = (float*)smem;            // 9216 floats
    int co = blk - 16384;
    const float* src = w1 + (size_t)co * 9216;
    for (int i = t; i < 9216; i += 256) wl[i] = src[i];
    __syncthreads();
    // wt layout: [ts = tap*32 + kb2][co 512][kc2 32]
    for (int i = t; i < 9216; i += 256) {
      int tap = i >> 10;
      int ci = i - (tap << 10);
      int kb2 = ci >> 5, kc2 = ci & 31;
      wt[((size_t)tap * 32 + kb2) * 16384 + co * 32 + kc2] = f2bf(wl[ci * 9 + tap]);
    }
  } else if (blk < 17920) {
    int e = (blk - 16896) * 256 + t;     // t_w: K=1024
    int p = e >> 10, k = e & 1023;
    wTt[e] = f2bf(tw[(size_t)k * 256 + p]);
  } else {
    int e = (blk - 17920) * 256 + t;     // s_w: K=512
    int p = e >> 9, k = e & 511;
    wTs[e] = f2bf(sw[(size_t)k * 256 + p]);
  }
}

// --------------------------- K1: conv GEMM, BK=32, 2 blocks/CU -------------
// A = im2col(tpad) [65536 x 9216], B = wt [512 x 9216], C partial -> heat.
// Per K32-tile: ph0 {8 open ds_reads (af0-3,bf0-3), stage A(T+1), barrier,
// lgkm0, prio1, 16 MFMA (i0-3), tail af4-7, prio0, barrier}; ph1 {stage
// B(T+1), barrier, lgkm0, prio1, 16 MFMA (i4-7), prio0, vmcnt(0), barrier}.
// vmcnt(0) before the boundary barrier publishes buf(T+1) block-wide.
// Restage safety: last reads of a buffer drain at the following MID lgkm0,
// >=1 barrier before its restaging.  64B LDS rows; chunk c of row r stored
// at slot c^((r>>1)&3); staged via pre-swizzled per-lane global source
// (l&3)^((l>>3)&3); fragment reads land 2 lanes/bank (free).
#define CSTAGE_A(buf, ts, h) do {                                             \
    int tap_ = (ts) >> 5, kb_ = (ts) & 31;                                    \
    int ky_ = tap_ / 3, kx_ = tap_ - ky_ * 3;                                 \
    unsigned o_ = (unsigned)(((ky_ * 66 + kx_) << 10) + (kb_ << 5));          \
    gld16(tpad + aoff[h] + o_,                                                \
          (char*)(As[buf] + ((wid * 16 + (h) * 128) << 5)));                  \
  } while (0)

#define CSTAGE_B(buf, ts, h) do {                                             \
    unsigned o_ = (unsigned)((ts) << 14);                                     \
    gld16(wt + boff[h] + o_,                                                  \
          (char*)(Bs[buf] + ((wid * 16 + (h) * 128) << 5)));                  \
  } while (0)

#define CLDA(R, buf, i)                                                       \
  R = *(const s16x8*)(const void*)(                                           \
      &As[buf][(wm * 128 + (i) * 16 + l15) * 32 + ((quad ^ swq) * 8)]);

#define CLDB(R, buf, j)                                                       \
  R = *(const s16x8*)(const void*)(                                           \
      &Bs[buf][(wn * 64 + (j) * 16 + l15) * 32 + ((quad ^ swq) * 8)]);

#define CMFMA(i0)                                                             \
  _Pragma("unroll") for (int i_ = 0; i_ < 4; ++i_)                            \
  _Pragma("unroll") for (int j_ = 0; j_ < 4; ++j_)                            \
    acc[(i0) + i_][j_] = __builtin_amdgcn_mfma_f32_16x16x32_bf16(             \
        af[(i0) + i_], bf[j_], acc[(i0) + i_][j_], 0, 0, 0);

#define PHASE_MID()                                                           \
  __builtin_amdgcn_s_barrier();                                               \
  asm volatile("s_waitcnt lgkmcnt(0)" ::: "memory");                          \
  __builtin_amdgcn_sched_barrier(0);                                          \
  __builtin_amdgcn_s_setprio(1)

#define PHASE_END()                                                           \
  __builtin_amdgcn_s_setprio(0);                                              \
  __builtin_amdgcn_sched_barrier(0);                                          \
  __builtin_amdgcn_s_barrier()

#define PHASE_END_VM0()                                                       \
  __builtin_amdgcn_s_setprio(0);                                              \
  __builtin_amdgcn_sched_barrier(0);                                          \
  asm volatile("s_waitcnt vmcnt(0)" ::: "memory");                            \
  __builtin_amdgcn_s_barrier()

#define CTILE(bufc, bufn, tsn)                                                \
    CLDA(af[0], bufc, 0); CLDA(af[1], bufc, 1);                               \
    CLDA(af[2], bufc, 2); CLDA(af[3], bufc, 3);                               \
    CLDB(bf[0], bufc, 0); CLDB(bf[1], bufc, 1);                               \
    CLDB(bf[2], bufc, 2); CLDB(bf[3], bufc, 3);                               \
    CSTAGE_A(bufn, tsn, 0); CSTAGE_A(bufn, tsn, 1);                           \
    PHASE_MID();                                                              \
    CMFMA(0);                                                                 \
    CLDA(af[4], bufc, 4); CLDA(af[5], bufc, 5);                               \
    CLDA(af[6], bufc, 6); CLDA(af[7], bufc, 7);                               \
    PHASE_END();                                                              \
    CSTAGE_B(bufn, tsn, 0); CSTAGE_B(bufn, tsn, 1);                           \
    PHASE_MID();                                                              \
    CMFMA(4);                                                                 \
    PHASE_END_VM0();

__global__ __launch_bounds__(512, 4) void k_conv(
    const unsigned short* __restrict__ tpad, const unsigned short* __restrict__ wt,
    const float* __restrict__ b1, const float* __restrict__ w2,
    float* __restrict__ heat) {
  __shared__ __align__(16) unsigned short As[2][256 * 32];
  __shared__ __align__(16) unsigned short Bs[2][256 * 32];
  int bid = blockIdx.x;
  // bijective XCD swizzle (512 % 8 == 0): adjacent swz share the A panel.
  int swz = (bid & 7) * 64 + (bid >> 3);
  int nt = swz & 1, mt = swz >> 1;
  int m0 = mt * 256, n0 = nt * 256;
  int t = threadIdx.x, wid = t >> 6, lane = t & 63;
  int wm = wid >> 2, wn = wid & 3;
  int quad = lane >> 4, l15 = lane & 15;
  int swq = (l15 >> 1) & 3;

  // staging: each gld16 covers 16 rows x 4 slots; lane l -> row base+(l>>2),
  // dest slot l&3, source chunk (l&3)^((l>>3)&3)  [slot s of row r holds
  // chunk s^((r>>1)&3), base%16==0]
  int srcChunk = (lane & 3) ^ ((lane >> 3) & 3);
  unsigned aoff[2], boff[2];
#pragma unroll
  for (int h = 0; h < 2; ++h) {
    int row = wid * 16 + h * 128 + (lane >> 2);
    int m = m0 + row;
    int b = m >> 12, y = (m >> 6) & 63, x = m & 63;
    aoff[h] = (unsigned)((((b * 66 + y) * 66 + x) << 10) + srcChunk * 8);
    boff[h] = (unsigned)(((n0 + row) << 5) + srcChunk * 8);
  }

  f32x4 acc[8][4];
  const f32x4 fz = {0.f, 0.f, 0.f, 0.f};
#pragma unroll
  for (int i = 0; i < 8; ++i)
#pragma unroll
    for (int j = 0; j < 4; ++j) acc[i][j] = fz;

  // prologue: stage tile 0 into buf0
  CSTAGE_A(0, 0, 0); CSTAGE_A(0, 0, 1);
  CSTAGE_B(0, 0, 0); CSTAGE_B(0, 0, 1);
  asm volatile("s_waitcnt vmcnt(0)" ::: "memory");
  __builtin_amdgcn_s_barrier();

  s16x8 af[8], bf[4];
  for (int T = 0; T < 288; T += 2) {
    int ts1 = T + 1;                       // <= 287 always
    int ts2 = (T + 2 < 288) ? T + 2 : 287; // clamp (harmless dup stage)
    CTILE(0, 1, ts1);
    CTILE(1, 0, ts2);
  }

  // epilogue: ReLU(conv1+b1) . w2 over this block's 256 co, atomicAdd.
  float w2v[4], b1v[4];
#pragma unroll
  for (int j = 0; j < 4; ++j) {
    int co = n0 + wn * 64 + j * 16 + l15;
    w2v[j] = w2[co];
    b1v[j] = b1[co];
  }
#pragma unroll
  for (int i = 0; i < 8; ++i) {
#pragma unroll
    for (int r = 0; r < 4; ++r) {
      float part = 0.f;
#pragma unroll
      for (int j = 0; j < 4; ++j) {
        float v = acc[i][j][r] + b1v[j];
        v = fmaxf(v, 0.f);
        part += v * w2v[j];
      }
#pragma unroll
      for (int msk = 1; msk < 16; msk <<= 1) part += __shfl_xor(part, msk, 64);
      if (l15 == 0) atomicAdd(&heat[m0 + wm * 128 + i * 16 + quad * 4 + r], part);
    }
  }
}

// --------------------------- threefry (JAX partitionable) ------------------
__device__ __forceinline__ unsigned rotl32(unsigned x, int d) {
  return (x << d) | (x >> (32 - d));
}
__device__ unsigned threefry_bits(unsigned lo) {
  const unsigned k0 = 0u, k1 = 42u;
  const unsigned k2 = 0x1BD11BDAu ^ k0 ^ k1;
  unsigned x0 = 0u + k0, x1 = lo + k1;
#define TF_R4(a, bq, c, d)                                \
  x0 += x1; x1 = rotl32(x1, a); x1 ^= x0;                 \
  x0 += x1; x1 = rotl32(x1, bq); x1 ^= x0;                \
  x0 += x1; x1 = rotl32(x1, c); x1 ^= x0;                 \
  x0 += x1; x1 = rotl32(x1, d); x1 ^= x0;
  TF_R4(13, 15, 26, 6)  x0 += k1; x1 += k2 + 1u;
  TF_R4(17, 29, 16, 24) x0 += k2; x1 += k0 + 2u;
  TF_R4(13, 15, 26, 6)  x0 += k0; x1 += k1 + 3u;
  TF_R4(17, 29, 16, 24) x0 += k1; x1 += k2 + 4u;
  TF_R4(13, 15, 26, 6)  x0 += k2; x1 += k0 + 5u;
#undef TF_R4
  return x0 ^ x1;
}

// ----------------- K2: fused softplus/prob/score + topk + sal --------------
__global__ void k_score_topk_sal(const float* __restrict__ heat,
                                 const float* __restrict__ b2p,
                                 float* __restrict__ out_hm,
                                 int* __restrict__ idx_sel,
                                 int* __restrict__ bd, int* __restrict__ cnt,
                                 int* __restrict__ nbc) {
  __shared__ float hmp[4096];
  __shared__ unsigned keys[4096];
  __shared__ unsigned hist[256];
  __shared__ unsigned suf[256];
  __shared__ unsigned wsum[4];
  __shared__ unsigned sel[2];
  __shared__ int wpos;
  __shared__ int idxl[256];
  __shared__ float l4[4];
  int b = blockIdx.x, t = threadIdx.x;
  float b2 = b2p[0];
  float lsum = 0.f;
#pragma unroll
  for (int j = 0; j < 16; ++j) {
    int e = j * 256 + t;
    float x = heat[b * 4096 + e] + b2;
    float sp = fmaxf(x, 0.f) + log1pf(expf(-fabsf(x)));
    hmp[e] = sp;
    lsum += sp;
  }
  float S = block_sum(lsum, l4);
  float denom = S + 1e-6f;
#pragma unroll
  for (int j = 0; j < 16; ++j) {
    int e = j * 256 + t;
    float sp = hmp[e];
    out_hm[b * 4096 + e] = sp;
    float lp = logf(sp / denom + 1e-12f);
    unsigned bits = threefry_bits((unsigned)(b * 4096 + e));
    float u01 = __uint_as_float((bits >> 9) | 0x3f800000u) - 1.0f;
    float u = fmaxf(1e-8f, u01 * (1.0f - 1e-8f) + 1e-8f);
    float gum = -logf(-logf(u));
    float sc = lp + gum;
    unsigned uu = __float_as_uint(sc);
    uu = (uu >> 31) ? ~uu : (uu | 0x80000000u);
    keys[e] = uu;
  }
  if (t == 0) wpos = 0;
  unsigned prefix = 0, hmask = 0, r = 256;
  for (int pass = 0; pass < 4; ++pass) {
    int shift = 24 - 8 * pass;
    hist[t] = 0;
    __syncthreads();
#pragma unroll
    for (int j = 0; j < 16; ++j) {
      unsigned u = keys[j * 256 + t];
      if ((u & hmask) == prefix) atomicAdd(&hist[(u >> shift) & 255u], 1u);
    }
    __syncthreads();
    // wave-level suffix scan over 256 bins (4 waves x 64 lanes)
    unsigned v = hist[t];
#pragma unroll
    for (int off = 1; off < 64; off <<= 1) {
      unsigned o = __shfl_down(v, off, 64);
      if ((t & 63) + off < 64) v += o;
    }
    if ((t & 63) == 0) wsum[t >> 6] = v;
    __syncthreads();
    for (int ww = (t >> 6) + 1; ww < 4; ++ww) v += wsum[ww];
    suf[t] = v;
    __syncthreads();
    unsigned above = (t < 255) ? suf[t + 1] : 0u;
    if (suf[t] >= r && above < r) {
      sel[0] = (unsigned)t;
      sel[1] = above;
    }
    __syncthreads();
    prefix |= sel[0] << shift;
    hmask |= 0xFFu << shift;
    r -= sel[1];
    __syncthreads();
  }
#pragma unroll
  for (int j = 0; j < 16; ++j) {
    int e = j * 256 + t;
    if (keys[e] > prefix) {
      int s = atomicAdd(&wpos, 1);
      idx_sel[b * 256 + s] = e;
      idxl[s] = e;
    }
  }
  __syncthreads();
#pragma unroll
  for (int j = 0; j < 16; ++j) {
    int e = j * 256 + t;
    if (keys[e] == prefix) {
      int s = atomicAdd(&wpos, 1);
      if (s < 256) {
        idx_sel[b * 256 + s] = e;
        idxl[s] = e;
      }
    }
  }
  __syncthreads();
  // ---- saliency / bd (former k_sal) ----
  int idx = idxl[t];
  int px = idx & 63, py = idx >> 6;
  float v = 0.f;
  if (py > 0) {
    if (px > 0) v += hmp[(py - 1) * 64 + px - 1];
    v += hmp[(py - 1) * 64 + px];
  }
  if (px > 0) v += hmp[py * 64 + px - 1];
  v += hmp[py * 64 + px];
  float sal = 0.25f * v;
  float mx = sal;
  for (int m = 32; m; m >>= 1) mx = fmaxf(mx, __shfl_xor(mx, m, 64));
  if ((t & 63) == 0) l4[t >> 6] = mx;
  __syncthreads();
  mx = fmaxf(fmaxf(l4[0], l4[1]), fmaxf(l4[2], l4[3]));
  __syncthreads();
  int bdv = sal > 0.6f * mx ? 1 : 0;
  bd[b * 256 + t] = bdv;
  float c = block_sum((float)bdv, l4);
  if (t == 0) {
    cnt[b] = (int)c;
    nbc[b] = 256 - (int)c;
  }
}

// --------------------------- K4a: teacher gather (vectorized) --------------
__global__ void k_gather_t(const unsigned short* __restrict__ tpad,
                           const int* __restrict__ idx_sel,
                           unsigned short* __restrict__ ftb) {
  int t = threadIdx.x;
  int bn = blockIdx.x * 2 + (t >> 7);
  int tt = t & 127;
  int b = bn >> 8;
  int idx = idx_sel[bn];
  int px = idx & 63, py = idx >> 6;
  const unsigned short* base = tpad + ((size_t)(b * 66 + py) * 66 + px) * 1024 + tt * 8;
  s16x8 r0 = *(const s16x8*)(const void*)(base);
  s16x8 r1 = *(const s16x8*)(const void*)(base + 1024);
  s16x8 r2 = *(const s16x8*)(const void*)(base + 66 * 1024);
  s16x8 r3 = *(const s16x8*)(const void*)(base + 67 * 1024);
  s16x8 o;
#pragma unroll
  for (int k = 0; k < 8; ++k) {
    float v = bf2f((unsigned short)r0[k]) + bf2f((unsigned short)r1[k]) +
              bf2f((unsigned short)r2[k]) + bf2f((unsigned short)r3[k]);
    o[k] = (short)f2bf(0.25f * v);
  }
  *(s16x8*)(void*)&ftb[(size_t)bn * 1024 + tt * 8] = o;
}

// --------------------------- K4b: student gather (plane in LDS) ------------
__global__ void k_gather_s(const float* __restrict__ student,
                           const int* __restrict__ idx_sel,
                           unsigned short* __restrict__ fsbT) {
  __shared__ float plane[4096];
  int blk = blockIdx.x;
  int b = blk >> 9, c = blk & 511;
  int t = threadIdx.x;
  const float4* g4 = (const float4*)(student + ((size_t)b * 512 + c) * 4096);
  float4* p4 = (float4*)plane;
  for (int i = t; i < 1024; i += 256) p4[i] = g4[i];
  __syncthreads();
  int idx = idx_sel[b * 256 + t];
  int px = idx & 63, py = idx >> 6;
  float v = 0.f;
  if (py > 0) {
    if (px > 0) v += plane[(py - 1) * 64 + px - 1];
    v += plane[(py - 1) * 64 + px];
  }
  if (px > 0) v += plane[py * 64 + px - 1];
  v += plane[py * 64 + px];
  fsbT[((size_t)b * 512 + c) * 256 + t] = f2bf(0.25f * v);
}

// --------------------------- K4c: fsbT -> fsb transpose --------------------
__global__ void k_fsb_tr(const unsigned short* __restrict__ fsbT,
                         unsigned short* __restrict__ fsb) {
  __shared__ unsigned short tile[64][65];
  int blk = blockIdx.x;
  int b = blk >> 5, ct = (blk >> 2) & 7, nt = blk & 3;
  int t = threadIdx.x;
#pragma unroll
  for (int it = 0; it < 16; ++it) {
    int e = it * 256 + t;
    int cl = e >> 6, n = e & 63;
    tile[cl][n] = fsbT[((size_t)(b * 512 + ct * 64 + cl)) * 256 + nt * 64 + n];
  }
  __syncthreads();
#pragma unroll
  for (int it = 0; it < 16; ++it) {
    int e = it * 256 + t;
    int n = e >> 6, cl = e & 63;
    fsb[((size_t)(b * 256 + nt * 64 + n)) * 512 + ct * 64 + cl] = tile[cl][n];
  }
}

// --------------------------- K5: both projection GEMMs ---------------------
__global__ __launch_bounds__(256) void k_proj_both(
    const unsigned short* __restrict__ At, const unsigned short* __restrict__ Wtt,
    const unsigned short* __restrict__ Asrc, const unsigned short* __restrict__ Wts,
    float* __restrict__ outt, float* __restrict__ outs) {
  __shared__ __align__(16) unsigned short Al[128 * 64];
  __shared__ __align__(16) unsigned short Bl[128 * 64];
  int g = blockIdx.x;
  const unsigned short* A;
  const unsigned short* Wt;
  float* outp;
  int K, bid;
  if (g < 64) { A = At; Wt = Wtt; outp = outt; K = 1024; bid = g; }
  else        { A = Asrc; Wt = Wts; outp = outs; K = 512; bid = g - 64; }
  int nt = bid & 1, mt = bid >> 1;
  int m0 = mt * 128, n0 = nt * 128;
  int t = threadIdx.x, wid = t >> 6, lane = t & 63;
  int wm = wid & 1, wn = wid >> 1;
  int quad = lane >> 4, l15 = lane & 15;

  f32x4 acc[4][4];
  const f32x4 fz = {0.f, 0.f, 0.f, 0.f};
#pragma unroll
  for (int i = 0; i < 4; ++i)
#pragma unroll
    for (int j = 0; j < 4; ++j) acc[i][j] = fz;

  int row4[4];
#pragma unroll
  for (int jj = 0; jj < 4; ++jj) row4[jj] = (wid * 4 + jj) * 8 + (lane >> 3);
  int kcol = (lane & 7) * 8;

  int nkb = K >> 6;
  for (int kb = 0; kb < nkb; ++kb) {
#pragma unroll
    for (int jj = 0; jj < 4; ++jj) {
      gld16(A + (size_t)(m0 + row4[jj]) * K + kb * 64 + kcol,
            (char*)Al + (wid * 4 + jj) * 1024);
      gld16(Wt + (size_t)(n0 + row4[jj]) * K + kb * 64 + kcol,
            (char*)Bl + (wid * 4 + jj) * 1024);
    }
    __syncthreads();
#pragma unroll
    for (int s = 0; s < 2; ++s) {
      s16x8 af[4], bf[4];
#pragma unroll
      for (int i = 0; i < 4; ++i) {
        af[i] = *(const s16x8*)(const void*)(Al + (wm * 64 + i * 16 + l15) * 64 + s * 32 + quad * 8);
        bf[i] = *(const s16x8*)(const void*)(Bl + (wn * 64 + i * 16 + l15) * 64 + s * 32 + quad * 8);
      }
#pragma unroll
      for (int i = 0; i < 4; ++i)
#pragma unroll
        for (int j = 0; j < 4; ++j)
          acc[i][j] = __builtin_amdgcn_mfma_f32_16x16x32_bf16(af[i], bf[j], acc[i][j], 0, 0, 0);
    }
    __syncthreads();
  }
#pragma unroll
  for (int i = 0; i < 4; ++i)
#pragma unroll
    for (int j = 0; j < 4; ++j)
#pragma unroll
      for (int r = 0; r < 4; ++r) {
        int m = m0 + wm * 64 + i * 16 + quad * 4 + r;
        int p = n0 + wn * 64 + j * 16 + l15;
        outp[(size_t)m * 256 + p] = acc[i][j][r];
      }
}

// --------- K5b: fused teacher+student LN/l2norm + pos + gafd ---------------
// Replaces k_ln + k_ln_s_pos; ftn/fsn never materialized.
__global__ void k_ln_both(const float* __restrict__ projt, const float* __restrict__ tb,
                          const float* __restrict__ tg, const float* __restrict__ tbe,
                          const float* __restrict__ projs, const float* __restrict__ sb,
                          const float* __restrict__ sg, const float* __restrict__ sbe,
                          unsigned short* __restrict__ outb,
                          float* __restrict__ pos, float* __restrict__ gsum) {
  __shared__ float l4[4];
  int row = blockIdx.x, t = threadIdx.x;
  // teacher
  float xt = projt[(size_t)row * 256 + t] + tb[t];
  float s1t = block_sum(xt, l4);
  float dt = xt - s1t * (1.f / 256.f);
  float s2t = block_sum(dt * dt, l4);
  float xnt = dt * rsqrtf(s2t * (1.f / 256.f) + 1e-5f) * tg[t] + tbe[t];
  float sst = block_sum(xnt * xnt, l4);
  float ot = xnt / fmaxf(sqrtf(sst), 1e-12f);
  // student
  float xs = projs[(size_t)row * 256 + t] + sb[t];
  float s1s = block_sum(xs, l4);
  float ds = xs - s1s * (1.f / 256.f);
  float s2s = block_sum(ds * ds, l4);
  float xns = ds * rsqrtf(s2s * (1.f / 256.f) + 1e-5f) * sg[t] + sbe[t];
  float sss = block_sum(xns * xns, l4);
  float os = xns / fmaxf(sqrtf(sss), 1e-12f);
  outb[(size_t)row * 256 + t] = f2bf(os);
  float sdot = block_sum(os * ot, l4);
  if (t == 0) pos[row] = sdot * 10.f;  // / TAU
  float dd = os - ot;
  float ssq = block_sum(dd * dd, l4);
  if (t == 0) atomicAdd(gsum, ssq);
}

// --------------------------- K7: neg matrix + masked LSE -------------------
// 128 blocks (8 n-tiles of 32 rows per batch) for 2x CU fill.
__global__ __launch_bounds__(256) void k_abcd_rows(
    const unsigned short* __restrict__ fsnb, const int* __restrict__ bd,
    const float* __restrict__ pos, float* __restrict__ rowloss) {
  __shared__ __align__(16) unsigned short Ab[32 * 64];
  __shared__ __align__(16) unsigned short Bb[256 * 64];
  __shared__ float mrg[32][4][2];
  int b = blockIdx.x >> 3, nb = blockIdx.x & 7;
  int n0 = nb * 32;
  int t = threadIdx.x, w = t >> 6, lane = t & 63, quad = lane >> 4, l15 = lane & 15;
  f32x4 acc[2][4];
  const f32x4 fz = {0.f, 0.f, 0.f, 0.f};
#pragma unroll
  for (int i = 0; i < 2; ++i)
#pragma unroll
    for (int j = 0; j < 4; ++j) acc[i][j] = fz;
  const unsigned short* fb = fsnb + (size_t)b * 256 * 256;

  for (int kc = 0; kc < 4; ++kc) {
    {
      int r = t >> 3, cc = (t & 7) * 8;
      *(uint4*)(void*)(Ab + r * 64 + cc) =
          *(const uint4*)(const void*)(fb + (size_t)(n0 + r) * 256 + kc * 64 + cc);
    }
#pragma unroll
    for (int it = 0; it < 4; ++it) {
      int m = it * 64 + (t >> 2), cc = (t & 3) * 16;
      const uint4* s = (const uint4*)(const void*)(fb + (size_t)m * 256 + kc * 64 + cc);
      *(uint4*)(void*)(Bb + m * 64 + cc) = s[0];
      *(uint4*)(void*)(Bb + m * 64 + cc + 8) = s[1];
    }
    __syncthreads();
#pragma unroll
    for (int s = 0; s < 2; ++s) {
      s16x8 af[2], bf[4];
#pragma unroll
      for (int i = 0; i < 2; ++i)
        af[i] = *(const s16x8*)(const void*)(Ab + (i * 16 + l15) * 64 + s * 32 + quad * 8);
#pragma unroll
      for (int j = 0; j < 4; ++j)
        bf[j] = *(const s16x8*)(const void*)(Bb + (w * 64 + j * 16 + l15) * 64 + s * 32 + quad * 8);
#pragma unroll
      for (int i = 0; i < 2; ++i)
#pragma unroll
        for (int j = 0; j < 4; ++j)
          acc[i][j] = __builtin_amdgcn_mfma_f32_16x16x32_bf16(af[i], bf[j], acc[i][j], 0, 0, 0);
    }
    __syncthreads();
  }

  int nbmask[4];
#pragma unroll
  for (int j = 0; j < 4; ++j) nbmask[j] = bd[b * 256 + w * 64 + j * 16 + l15];
#pragma unroll
  for (int i = 0; i < 2; ++i) {
#pragma unroll
    for (int r = 0; r < 4; ++r) {
      float mxv = -1e30f, se = 0.f;
#pragma unroll
      for (int j = 0; j < 4; ++j) {
        float v = nbmask[j] ? -1e30f : (acc[i][j][r] / 0.1f);
        if (v > mxv) {
          se = se * expf(mxv - v) + 1.f;
          mxv = v;
        } else {
          se += expf(v - mxv);
        }
      }
#pragma unroll
      for (int msk = 1; msk < 16; msk <<= 1) {
        float omx = __shfl_xor(mxv, msk, 64);
        float ose = __shfl_xor(se, msk, 64);
        float nm = fmaxf(mxv, omx);
        se = se * expf(mxv - nm) + ose * expf(omx - nm);
        mxv = nm;
      }
      if (l15 == 0) {
        mrg[i * 16 + quad * 4 + r][w][0] = mxv;
        mrg[i * 16 + quad * 4 + r][w][1] = se;
      }
    }
  }
  __syncthreads();
  if (t < 32) {
    float MX = -1e30f, SE = 0.f;
    for (int ww = 0; ww < 4; ++ww) {
      float omx = mrg[t][ww][0], ose = mrg[t][ww][1];
      float nm = fmaxf(MX, omx);
      SE = SE * expf(MX - nm) + ose * expf(omx - nm);
      MX = nm;
    }
    float p = pos[b * 256 + n0 + t];
    float nm = fmaxf(MX, p);
    float se2 = SE * expf(MX - nm) + expf(p - nm);
    rowloss[b * 256 + n0 + t] = nm + logf(se2) - p;
  }
}

// --------------------------- K8: final scalars -----------------------------
__global__ void k_final(const float* __restrict__ gsum, const float* __restrict__ rowloss,
                        const int* __restrict__ bd, const int* __restrict__ cnt,
                        const int* __restrict__ nbc, float* __restrict__ out) {
  __shared__ float l4[4];
  int t = threadIdx.x;
  float abcd_acc = 0.f, vnum = 0.f;
  for (int b = 0; b < 16; ++b) {
    float c = bd[b * 256 + t] ? rowloss[b * 256 + t] : 0.f;
    float s = block_sum(c, l4);
    if (t == 0) {
      float cb = (float)cnt[b];
      float per = s / fmaxf(cb, 1.f);
      if (cnt[b] > 0 && nbc[b] > 0) {
        abcd_acc += per;
        vnum += 1.f;
      }
    }
  }
  if (t == 0) {
    float gafd = gsum[0] / 1048576.f;
    float abcd = vnum > 0.f ? abcd_acc / fmaxf(vnum, 1.f) : 0.f;
    out[0] = gafd + 0.5f * abcd;
    out[1] = gafd;
    out[2] = abcd;
  }
}

// --------------------------- workspace layout ------------------------------
static constexpr size_t OFF_TPAD = 0;
static constexpr size_t TPAD_BYTES = (size_t)16 * 66 * 66 * 1024 * 2;
static constexpr size_t OFF_WT = OFF_TPAD + TPAD_BYTES;
static constexpr size_t WT_BYTES = (size_t)288 * 512 * 32 * 2;
static constexpr size_t OFF_HEAT = OFF_WT + WT_BYTES;
static constexpr size_t OFF_GSUM = OFF_HEAT + 262144;
static constexpr size_t OFF_HM = OFF_GSUM + 256;       // (unused, kept)
static constexpr size_t OFF_SC = OFF_HM + 262144;      // (unused, kept)
static constexpr size_t OFF_IDX = OFF_SC + 262144;
static constexpr size_t OFF_FTB = OFF_IDX + 16384;
static constexpr size_t OFF_FSB = OFF_FTB + (size_t)4096 * 1024 * 2;
static constexpr size_t OFF_FSBT = OFF_FSB + (size_t)4096 * 512 * 2;
static constexpr size_t OFF_WTT = OFF_FSBT + (size_t)4096 * 512 * 2;
static constexpr size_t OFF_WTS = OFF_WTT + (size_t)256 * 1024 * 2;
static constexpr size_t OFF_PRT = OFF_WTS + (size_t)256 * 512 * 2;
static constexpr size_t OFF_PRS = OFF_PRT + (size_t)4096 * 256 * 4;
static constexpr size_t OFF_FSNB = OFF_PRS + (size_t)4096 * 256 * 4;
static constexpr size_t OFF_POS = OFF_FSNB + (size_t)4096 * 256 * 2;
static constexpr size_t OFF_BD = OFF_POS + 16384;
static constexpr size_t OFF_CNT = OFF_BD + 16384;
static constexpr size_t OFF_NBC = OFF_CNT + 64;
static constexpr size_t OFF_RL = OFF_NBC + 64;

extern "C" void kernel_launch(void* const* d_in, const int* in_sizes, int n_in,
                              void* d_out, int out_size, void* d_ws, size_t ws_size,
                              hipStream_t stream) {
  const float* teacher = (const float*)d_in[0];
  const float* student = (const float*)d_in[1];
  const float* w1 = (const float*)d_in[2];
  const float* b1 = (const float*)d_in[3];
  const float* w2 = (const float*)d_in[4];
  const float* b2 = (const float*)d_in[5];
  const float* t_w = (const float*)d_in[6];
  const float* t_b = (const float*)d_in[7];
  const float* t_g = (const float*)d_in[8];
  const float* t_be = (const float*)d_in[9];
  const float* s_w = (const float*)d_in[10];
  const float* s_b = (const float*)d_in[11];
  const float* s_g = (const float*)d_in[12];
  const float* s_be = (const float*)d_in[13];
  float* out = (float*)d_out;

  char* ws = (char*)d_ws;
  unsigned short* tpad = (unsigned short*)(ws + OFF_TPAD);
  unsigned short* wt = (unsigned short*)(ws + OFF_WT);
  float* heat = (float*)(ws + OFF_HEAT);
  float* gsum = (float*)(ws + OFF_GSUM);
  int* idx_sel = (int*)(ws + OFF_IDX);
  unsigned short* ftb = (unsigned short*)(ws + OFF_FTB);
  unsigned short* fsb = (unsigned short*)(ws + OFF_FSB);
  unsigned short* fsbT = (unsigned short*)(ws + OFF_FSBT);
  unsigned short* wTt = (unsigned short*)(ws + OFF_WTT);
  unsigned short* wTs = (unsigned short*)(ws + OFF_WTS);
  float* projt = (float*)(ws + OFF_PRT);
  float* projs = (float*)(ws + OFF_PRS);
  unsigned short* fsnb = (unsigned short*)(ws + OFF_FSNB);
  float* pos = (float*)(ws + OFF_POS);
  int* bd = (int*)(ws + OFF_BD);
  int* cnt = (int*)(ws + OFF_CNT);
  int* nbc = (int*)(ws + OFF_NBC);
  float* rowloss = (float*)(ws + OFF_RL);

  hipMemsetAsync(ws + OFF_HEAT, 0, 262144 + 256, stream);  // heat + gsum

  k_pad_wprep<<<18432, 256, 0, stream>>>(teacher, tpad, w1, wt, t_w, wTt, s_w, wTs);
  k_conv<<<512, 512, 0, stream>>>(tpad, wt, b1, w2, heat);
  k_score_topk_sal<<<16, 256, 0, stream>>>(heat, b2, out + 3, idx_sel, bd, cnt, nbc);
  k_gather_t<<<2048, 256, 0, stream>>>(tpad, idx_sel, ftb);
  k_gather_s<<<8192, 256, 0, stream>>>(student, idx_sel, fsbT);
  k_fsb_tr<<<512, 256, 0, stream>>>(fsbT, fsb);
  k_proj_both<<<128, 256, 0, stream>>>(ftb, wTt, fsb, wTs, projt, projs);
  k_ln_both<<<4096, 256, 0, stream>>>(projt, t_b, t_g, t_be, projs, s_b, s_g, s_be,
                                      fsnb, pos, gsum);
  k_abcd_rows<<<128, 256, 0, stream>>>(fsnb, bd, pos, rowloss);
  k_final<<<1, 256, 0, stream>>>(gsum, rowloss, bd, cnt, nbc, out);
}

// Round 6
// 1119.898 us; speedup vs baseline: 5.7320x; 5.7320x over previous
//
#include <hip/hip_runtime.h>
#include <stdint.h>

// ---------------------------------------------------------------------------
// GAFD_ABCD pipeline on MI355X.  R9: conv + wt layout reverted EXACTLY to the
// verified R7 kernel (549 us; R8's occupancy attempt spilled acc -> scratch).
// Keeps R8's k_ln_both fusion (ftn/fsn round-trip eliminated, ~-70 us).
// ---------------------------------------------------------------------------

typedef float f32x4 __attribute__((ext_vector_type(4)));
typedef short s16x8 __attribute__((ext_vector_type(8)));

__device__ __forceinline__ unsigned short f2bf(float f) {
  unsigned u = __float_as_uint(f);
  u += 0x7fffu + ((u >> 16) & 1u);   // RNE
  return (unsigned short)(u >> 16);
}
__device__ __forceinline__ float bf2f(unsigned short h) {
  return __uint_as_float((unsigned)h << 16);
}

__device__ __forceinline__ void gld16(const void* g, void* l) {
  __builtin_amdgcn_global_load_lds(
      (const __attribute__((address_space(1))) void*)g,
      (__attribute__((address_space(3))) void*)l, 16, 0, 0);
}

__device__ __forceinline__ float block_sum(float v, float* l4) {
  for (int m = 32; m; m >>= 1) v += __shfl_xor(v, m, 64);
  int wid = threadIdx.x >> 6;
  if ((threadIdx.x & 63) == 0) l4[wid] = v;
  __syncthreads();
  float r = l4[0] + l4[1] + l4[2] + l4[3];
  __syncthreads();
  return r;
}

// ---------------- K0: fused pad-transpose + weight prep --------------------
// blocks 0..16383: teacher pad-transpose.  16384..16895: conv wprep.
// 16896..17919: t_w transpose.  17920..18431: s_w transpose.
__global__ void k_pad_wprep(const float* __restrict__ teacher,
                            unsigned short* __restrict__ tpad,
                            const float* __restrict__ w1,
                            unsigned short* __restrict__ wt,
                            const float* __restrict__ tw, unsigned short* __restrict__ wTt,
                            const float* __restrict__ sw, unsigned short* __restrict__ wTs) {
  __shared__ __align__(16) char smem[36864];
  int blk = blockIdx.x, t = threadIdx.x;
  if (blk < 16384) {
    unsigned short* lds = (unsigned short*)smem;  // 64*65 shorts
    int cb = blk & 15, y = (blk >> 4) & 63, b = blk >> 10;
#pragma unroll
    for (int it = 0; it < 4; ++it) {
      int idx = it * 256 + t;            // 1024 float4 items
      int cl = idx >> 4, x4 = (idx & 15) * 4;
      float4 v = *(const float4*)&teacher[(size_t)(b * 1024 + cb * 64 + cl) * 4096 + y * 64 + x4];
      lds[cl * 65 + x4 + 0] = f2bf(v.x);
      lds[cl * 65 + x4 + 1] = f2bf(v.y);
      lds[cl * 65 + x4 + 2] = f2bf(v.z);
      lds[cl * 65 + x4 + 3] = f2bf(v.w);
    }
    __syncthreads();
    size_t obase = ((size_t)(b * 66 + y + 1) * 66 + 1) * 1024 + cb * 64;
#pragma unroll
    for (int it = 0; it < 2; ++it) {
      int wi = it * 256 + t;             // 512 items: 64 x * 8 chunk-groups
      int x = wi >> 3, c0 = (wi & 7) * 8;
      s16x8 v;
#pragma unroll
      for (int k2 = 0; k2 < 8; ++k2) v[k2] = (short)lds[(c0 + k2) * 65 + x];
      *(s16x8*)(void*)&tpad[obase + (size_t)x * 1024 + c0] = v;
    }
    if (y == 0) {
      for (int idx = t; idx < 66 * 64; idx += 256) {
        int col = idx >> 6, cl = idx & 63;
        tpad[((size_t)(b * 66) * 66 + col) * 1024 + cb * 64 + cl] = 0;
      }
    }
    if (y == 63) {
      for (int idx = t; idx < 66 * 64; idx += 256) {
        int col = idx >> 6, cl = idx & 63;
        tpad[((size_t)(b * 66 + 65) * 66 + col) * 1024 + cb * 64 + cl] = 0;
      }
    }
    if (t < 128) {
      int col = (t >= 64) ? 65 : 0;
      int cl = t & 63;
      tpad[((size_t)(b * 66 + y + 1) * 66 + col) * 1024 + cb * 64 + cl] = 0;
    }
  } else if (blk < 16896) {
    float* wl = (float*)smem;            // 9216 floats
    int co = blk - 16384;
    const float* src = w1 + (size_t)co * 9216;
    for (int i = t; i < 9216; i += 256) wl[i] = src[i];
    __syncthreads();
    for (int i = t; i < 9216; i += 256) {
      int tap = i >> 10;
      int ci = i - (tap << 10);
      int kb = ci >> 6, kc = ci & 63;
      wt[(size_t)tap * 524288 + (size_t)kb * 32768 + co * 64 + kc] = f2bf(wl[ci * 9 + tap]);
    }
  } else if (blk < 17920) {
    int e = (blk - 16896) * 256 + t;     // t_w: K=1024
    int p = e >> 10, k = e & 1023;
    wTt[e] = f2bf(tw[(size_t)k * 256 + p]);
  } else {
    int e = (blk - 17920) * 256 + t;     // s_w: K=512
    int p = e >> 9, k = e & 511;
    wTs[e] = f2bf(sw[(size_t)k * 256 + p]);
  }
}

// --------------------------- K1: conv GEMM, 256^2 8-phase (R7) -------------
// A = im2col(tpad) [65536 x 9216], B = wt [512 x 9216], C partial -> heat.
// R7 ledger (per-wave, steady state; each STAGE = 2 gld16):
//  entry: 4 outstanding (prev B1 ph6/7)
//  ph0 +A1h0=6, ph1 +A1h1=8, ph2 +B0h0=10, END vmcnt(2) -> completes
//    prevB1(4)+A1(4): buf1(T1) PUBLISHED; 2 left (B0h0)
//  ph3 +B0h1=4 [tail reads buf1], ph4 +A0h0=6, ph5 +A0h1=8,
//  ph6 +B1h0=10, END vmcnt(2) -> completes B0(4)+A0(4): buf0(T0+2)
//    PUBLISHED; 2 left (B1h0)
//  ph7 +B1h1=4 [tail reads buf0 for next group], plain END.
#define STAGE_A(buf, ts, h) do {                                              \
    int tap_ = (ts) >> 4, kb_ = (ts) & 15;                                    \
    int ky_ = tap_ / 3, kx_ = tap_ - ky_ * 3;                                 \
    unsigned o_ = (unsigned)(((ky_ * 66 + kx_) << 10) + (kb_ << 6));          \
    gld16(tpad + aoff[(h) * 2 + 0] + o_,                                      \
          (char*)(As[buf] + (((h) * 128 + wid * 8) << 6)));                   \
    gld16(tpad + aoff[(h) * 2 + 1] + o_,                                      \
          (char*)(As[buf] + (((h) * 128 + 64 + wid * 8) << 6)));              \
  } while (0)

#define STAGE_B(buf, ts, h) do {                                              \
    int tap_ = (ts) >> 4, kb_ = (ts) & 15;                                    \
    unsigned o_ = (unsigned)((tap_ << 19) + (kb_ << 15));                     \
    gld16(wt + boff[(h) * 2 + 0] + o_,                                       \
          (char*)(Bs[buf] + (((h) * 128 + wid * 8) << 6)));                   \
    gld16(wt + boff[(h) * 2 + 1] + o_,                                       \
          (char*)(Bs[buf] + (((h) * 128 + 64 + wid * 8) << 6)));              \
  } while (0)

#define LDA8(AF, buf, i0)                                                     \
  _Pragma("unroll") for (int i_ = 0; i_ < 4; ++i_)                            \
  _Pragma("unroll") for (int s_ = 0; s_ < 2; ++s_)                            \
    AF[i_][s_] = *(const s16x8*)(const void*)(                                \
        &As[buf][(wm * 128 + ((i0) + i_) * 16 + l15) * 64 +                   \
                 ((s_ * 4 + quad) ^ sw7) * 8]);

#define LDB4(BF, buf, j0)                                                     \
  _Pragma("unroll") for (int j_ = 0; j_ < 2; ++j_)                            \
  _Pragma("unroll") for (int s_ = 0; s_ < 2; ++s_)                            \
    BF[j_][s_] = *(const s16x8*)(const void*)(                                \
        &Bs[buf][(wn * 64 + ((j0) + j_) * 16 + l15) * 64 +                    \
                 ((s_ * 4 + quad) ^ sw7) * 8]);

#define MFMA16(AF, BF, i0, j0)                                                \
  _Pragma("unroll") for (int i_ = 0; i_ < 4; ++i_)                            \
  _Pragma("unroll") for (int j_ = 0; j_ < 2; ++j_)                            \
  _Pragma("unroll") for (int s_ = 0; s_ < 2; ++s_)                            \
    acc[(i0) + i_][(j0) + j_] = __builtin_amdgcn_mfma_f32_16x16x32_bf16(      \
        AF[i_][s_], BF[j_][s_], acc[(i0) + i_][(j0) + j_], 0, 0, 0);

#define PHASE_MID()                                                           \
  __builtin_amdgcn_s_barrier();                                               \
  asm volatile("s_waitcnt lgkmcnt(0)" ::: "memory");                          \
  __builtin_amdgcn_sched_barrier(0);                                          \
  __builtin_amdgcn_s_setprio(1)

#define PHASE_END()                                                           \
  __builtin_amdgcn_s_setprio(0);                                              \
  __builtin_amdgcn_sched_barrier(0);                                          \
  __builtin_amdgcn_s_barrier()

#define PHASE_END_VM2()                                                       \
  __builtin_amdgcn_s_setprio(0);                                              \
  __builtin_amdgcn_sched_barrier(0);                                          \
  asm volatile("s_waitcnt vmcnt(2)" ::: "memory");                            \
  __builtin_amdgcn_s_barrier()

__global__ __launch_bounds__(512, 2) void k_conv(
    const unsigned short* __restrict__ tpad, const unsigned short* __restrict__ wt,
    const float* __restrict__ b1, const float* __restrict__ w2,
    float* __restrict__ heat) {
  __shared__ __align__(16) unsigned short As[2][256 * 64];
  __shared__ __align__(16) unsigned short Bs[2][256 * 64];
  int bid = blockIdx.x;
  // bijective XCD swizzle (512 % 8 == 0): adjacent swz share the A panel.
  int swz = (bid & 7) * 64 + (bid >> 3);
  int nt = swz & 1, mt = swz >> 1;
  int m0 = mt * 256, n0 = nt * 256;
  int t = threadIdx.x, wid = t >> 6, lane = t & 63;
  int wm = wid >> 2, wn = wid & 3;
  int quad = lane >> 4, l15 = lane & 15;
  int sw7 = l15 & 7;

  int srcChunk = (t & 7) ^ ((t >> 3) & 7);
  unsigned aoff[4], boff[4];
#pragma unroll
  for (int v = 0; v < 4; ++v) {
    int row = (v >> 1) * 128 + (v & 1) * 64 + (t >> 3);
    int m = m0 + row;
    int b = m >> 12, y = (m >> 6) & 63, x = m & 63;
    aoff[v] = (unsigned)((((b * 66 + y) * 66 + x) << 10) + srcChunk * 8);
    boff[v] = (unsigned)(((n0 + row) << 6) + srcChunk * 8);
  }

  f32x4 acc[8][4];
  const f32x4 fz = {0.f, 0.f, 0.f, 0.f};
#pragma unroll
  for (int i = 0; i < 8; ++i)
#pragma unroll
    for (int j = 0; j < 4; ++j) acc[i][j] = fz;

  // prologue: tile0 (B then A) into buf0, B of tile1 into buf1.
  STAGE_B(0, 0, 0); STAGE_B(0, 0, 1);
  STAGE_A(0, 0, 0); STAGE_A(0, 0, 1);
  STAGE_B(1, 1, 0); STAGE_B(1, 1, 1);
  asm volatile("s_waitcnt vmcnt(4)" ::: "memory");
  __builtin_amdgcn_s_barrier();

  // peeled initial reads of buf0 (tile 0); loop-carried af/bf01 thereafter.
  s16x8 af[4][2], bf01[2][2], bf23[2][2];
  LDA8(af, 0, 0);
  LDB4(bf01, 0, 0);

  for (int it2 = 0; it2 < 72; ++it2) {
    int T1 = it2 * 2 + 1;
    int tsA = (T1 + 1 <= 143) ? T1 + 1 : 143;   // T0+2
    int tsB = (T1 + 2 <= 143) ? T1 + 2 : 143;   // T1+2

    // ---- K-tile T0 (buf0) ----
    STAGE_A(1, T1, 0);
    PHASE_MID();
    MFMA16(af, bf01, 0, 0);
    LDB4(bf23, 0, 2);            // tail for ph1
    PHASE_END();

    STAGE_A(1, T1, 1);
    PHASE_MID();
    MFMA16(af, bf23, 0, 2);
    LDA8(af, 0, 4);              // tail for ph2
    PHASE_END();

    STAGE_B(0, tsA, 0);
    PHASE_MID();
    MFMA16(af, bf01, 4, 0);
    PHASE_END_VM2();             // publishes buf1 (T1)

    STAGE_B(0, tsA, 1);
    PHASE_MID();
    MFMA16(af, bf23, 4, 2);
    LDA8(af, 1, 0);              // tail for ph4 (buf1, published ph2-end)
    LDB4(bf01, 1, 0);
    PHASE_END();

    // ---- K-tile T1 (buf1) ----
    STAGE_A(0, tsA, 0);
    PHASE_MID();
    MFMA16(af, bf01, 0, 0);
    LDB4(bf23, 1, 2);            // tail for ph5
    PHASE_END();

    STAGE_A(0, tsA, 1);
    PHASE_MID();
    MFMA16(af, bf23, 0, 2);
    LDA8(af, 1, 4);              // tail for ph6
    PHASE_END();

    STAGE_B(1, tsB, 0);
    PHASE_MID();
    MFMA16(af, bf01, 4, 0);
    PHASE_END_VM2();             // publishes buf0 (T0+2)

    STAGE_B(1, tsB, 1);
    PHASE_MID();
    MFMA16(af, bf23, 4, 2);
    LDA8(af, 0, 0);              // tail for next ph0 (buf0, published ph6-end)
    LDB4(bf01, 0, 0);
    PHASE_END();
  }

  // epilogue: ReLU(conv1+b1) . w2 over this block's 256 co, atomicAdd.
  float w2v[4], b1v[4];
#pragma unroll
  for (int j = 0; j < 4; ++j) {
    int co = n0 + wn * 64 + j * 16 + l15;
    w2v[j] = w2[co];
    b1v[j] = b1[co];
  }
#pragma unroll
  for (int i = 0; i < 8; ++i) {
#pragma unroll
    for (int r = 0; r < 4; ++r) {
      float part = 0.f;
#pragma unroll
      for (int j = 0; j < 4; ++j) {
        float v = acc[i][j][r] + b1v[j];
        v = fmaxf(v, 0.f);
        part += v * w2v[j];
      }
#pragma unroll
      for (int msk = 1; msk < 16; msk <<= 1) part += __shfl_xor(part, msk, 64);
      if (l15 == 0) atomicAdd(&heat[m0 + wm * 128 + i * 16 + quad * 4 + r], part);
    }
  }
}

// --------------------------- threefry (JAX partitionable) ------------------
__device__ __forceinline__ unsigned rotl32(unsigned x, int d) {
  return (x << d) | (x >> (32 - d));
}
__device__ unsigned threefry_bits(unsigned lo) {
  const unsigned k0 = 0u, k1 = 42u;
  const unsigned k2 = 0x1BD11BDAu ^ k0 ^ k1;
  unsigned x0 = 0u + k0, x1 = lo + k1;
#define TF_R4(a, bq, c, d)                                \
  x0 += x1; x1 = rotl32(x1, a); x1 ^= x0;                 \
  x0 += x1; x1 = rotl32(x1, bq); x1 ^= x0;                \
  x0 += x1; x1 = rotl32(x1, c); x1 ^= x0;                 \
  x0 += x1; x1 = rotl32(x1, d); x1 ^= x0;
  TF_R4(13, 15, 26, 6)  x0 += k1; x1 += k2 + 1u;
  TF_R4(17, 29, 16, 24) x0 += k2; x1 += k0 + 2u;
  TF_R4(13, 15, 26, 6)  x0 += k0; x1 += k1 + 3u;
  TF_R4(17, 29, 16, 24) x0 += k1; x1 += k2 + 4u;
  TF_R4(13, 15, 26, 6)  x0 += k2; x1 += k0 + 5u;
#undef TF_R4
  return x0 ^ x1;
}

// ----------------- K2: fused softplus/prob/score + topk + sal --------------
__global__ void k_score_topk_sal(const float* __restrict__ heat,
                                 const float* __restrict__ b2p,
                                 float* __restrict__ out_hm,
                                 int* __restrict__ idx_sel,
                                 int* __restrict__ bd, int* __restrict__ cnt,
                                 int* __restrict__ nbc) {
  __shared__ float hmp[4096];
  __shared__ unsigned keys[4096];
  __shared__ unsigned hist[256];
  __shared__ unsigned suf[256];
  __shared__ unsigned wsum[4];
  __shared__ unsigned sel[2];
  __shared__ int wpos;
  __shared__ int idxl[256];
  __shared__ float l4[4];
  int b = blockIdx.x, t = threadIdx.x;
  float b2 = b2p[0];
  float lsum = 0.f;
#pragma unroll
  for (int j = 0; j < 16; ++j) {
    int e = j * 256 + t;
    float x = heat[b * 4096 + e] + b2;
    float sp = fmaxf(x, 0.f) + log1pf(expf(-fabsf(x)));
    hmp[e] = sp;
    lsum += sp;
  }
  float S = block_sum(lsum, l4);
  float denom = S + 1e-6f;
#pragma unroll
  for (int j = 0; j < 16; ++j) {
    int e = j * 256 + t;
    float sp = hmp[e];
    out_hm[b * 4096 + e] = sp;
    float lp = logf(sp / denom + 1e-12f);
    unsigned bits = threefry_bits((unsigned)(b * 4096 + e));
    float u01 = __uint_as_float((bits >> 9) | 0x3f800000u) - 1.0f;
    float u = fmaxf(1e-8f, u01 * (1.0f - 1e-8f) + 1e-8f);
    float gum = -logf(-logf(u));
    float sc = lp + gum;
    unsigned uu = __float_as_uint(sc);
    uu = (uu >> 31) ? ~uu : (uu | 0x80000000u);
    keys[e] = uu;
  }
  if (t == 0) wpos = 0;
  unsigned prefix = 0, hmask = 0, r = 256;
  for (int pass = 0; pass < 4; ++pass) {
    int shift = 24 - 8 * pass;
    hist[t] = 0;
    __syncthreads();
#pragma unroll
    for (int j = 0; j < 16; ++j) {
      unsigned u = keys[j * 256 + t];
      if ((u & hmask) == prefix) atomicAdd(&hist[(u >> shift) & 255u], 1u);
    }
    __syncthreads();
    // wave-level suffix scan over 256 bins (4 waves x 64 lanes)
    unsigned v = hist[t];
#pragma unroll
    for (int off = 1; off < 64; off <<= 1) {
      unsigned o = __shfl_down(v, off, 64);
      if ((t & 63) + off < 64) v += o;
    }
    if ((t & 63) == 0) wsum[t >> 6] = v;
    __syncthreads();
    for (int ww = (t >> 6) + 1; ww < 4; ++ww) v += wsum[ww];
    suf[t] = v;
    __syncthreads();
    unsigned above = (t < 255) ? suf[t + 1] : 0u;
    if (suf[t] >= r && above < r) {
      sel[0] = (unsigned)t;
      sel[1] = above;
    }
    __syncthreads();
    prefix |= sel[0] << shift;
    hmask |= 0xFFu << shift;
    r -= sel[1];
    __syncthreads();
  }
#pragma unroll
  for (int j = 0; j < 16; ++j) {
    int e = j * 256 + t;
    if (keys[e] > prefix) {
      int s = atomicAdd(&wpos, 1);
      idx_sel[b * 256 + s] = e;
      idxl[s] = e;
    }
  }
  __syncthreads();
#pragma unroll
  for (int j = 0; j < 16; ++j) {
    int e = j * 256 + t;
    if (keys[e] == prefix) {
      int s = atomicAdd(&wpos, 1);
      if (s < 256) {
        idx_sel[b * 256 + s] = e;
        idxl[s] = e;
      }
    }
  }
  __syncthreads();
  // ---- saliency / bd (former k_sal) ----
  int idx = idxl[t];
  int px = idx & 63, py = idx >> 6;
  float v = 0.f;
  if (py > 0) {
    if (px > 0) v += hmp[(py - 1) * 64 + px - 1];
    v += hmp[(py - 1) * 64 + px];
  }
  if (px > 0) v += hmp[py * 64 + px - 1];
  v += hmp[py * 64 + px];
  float sal = 0.25f * v;
  float mx = sal;
  for (int m = 32; m; m >>= 1) mx = fmaxf(mx, __shfl_xor(mx, m, 64));
  if ((t & 63) == 0) l4[t >> 6] = mx;
  __syncthreads();
  mx = fmaxf(fmaxf(l4[0], l4[1]), fmaxf(l4[2], l4[3]));
  __syncthreads();
  int bdv = sal > 0.6f * mx ? 1 : 0;
  bd[b * 256 + t] = bdv;
  float c = block_sum((float)bdv, l4);
  if (t == 0) {
    cnt[b] = (int)c;
    nbc[b] = 256 - (int)c;
  }
}

// --------------------------- K4a: teacher gather (vectorized) --------------
__global__ void k_gather_t(const unsigned short* __restrict__ tpad,
                           const int* __restrict__ idx_sel,
                           unsigned short* __restrict__ ftb) {
  int t = threadIdx.x;
  int bn = blockIdx.x * 2 + (t >> 7);
  int tt = t & 127;
  int b = bn >> 8;
  int idx = idx_sel[bn];
  int px = idx & 63, py = idx >> 6;
  const unsigned short* base = tpad + ((size_t)(b * 66 + py) * 66 + px) * 1024 + tt * 8;
  s16x8 r0 = *(const s16x8*)(const void*)(base);
  s16x8 r1 = *(const s16x8*)(const void*)(base + 1024);
  s16x8 r2 = *(const s16x8*)(const void*)(base + 66 * 1024);
  s16x8 r3 = *(const s16x8*)(const void*)(base + 67 * 1024);
  s16x8 o;
#pragma unroll
  for (int k = 0; k < 8; ++k) {
    float v = bf2f((unsigned short)r0[k]) + bf2f((unsigned short)r1[k]) +
              bf2f((unsigned short)r2[k]) + bf2f((unsigned short)r3[k]);
    o[k] = (short)f2bf(0.25f * v);
  }
  *(s16x8*)(void*)&ftb[(size_t)bn * 1024 + tt * 8] = o;
}

// --------------------------- K4b: student gather (plane in LDS) ------------
__global__ void k_gather_s(const float* __restrict__ student,
                           const int* __restrict__ idx_sel,
                           unsigned short* __restrict__ fsbT) {
  __shared__ float plane[4096];
  int blk = blockIdx.x;
  int b = blk >> 9, c = blk & 511;
  int t = threadIdx.x;
  const float4* g4 = (const float4*)(student + ((size_t)b * 512 + c) * 4096);
  float4* p4 = (float4*)plane;
  for (int i = t; i < 1024; i += 256) p4[i] = g4[i];
  __syncthreads();
  int idx = idx_sel[b * 256 + t];
  int px = idx & 63, py = idx >> 6;
  float v = 0.f;
  if (py > 0) {
    if (px > 0) v += plane[(py - 1) * 64 + px - 1];
    v += plane[(py - 1) * 64 + px];
  }
  if (px > 0) v += plane[py * 64 + px - 1];
  v += plane[py * 64 + px];
  fsbT[((size_t)b * 512 + c) * 256 + t] = f2bf(0.25f * v);
}

// --------------------------- K4c: fsbT -> fsb transpose --------------------
__global__ void k_fsb_tr(const unsigned short* __restrict__ fsbT,
                         unsigned short* __restrict__ fsb) {
  __shared__ unsigned short tile[64][65];
  int blk = blockIdx.x;
  int b = blk >> 5, ct = (blk >> 2) & 7, nt = blk & 3;
  int t = threadIdx.x;
#pragma unroll
  for (int it = 0; it < 16; ++it) {
    int e = it * 256 + t;
    int cl = e >> 6, n = e & 63;
    tile[cl][n] = fsbT[((size_t)(b * 512 + ct * 64 + cl)) * 256 + nt * 64 + n];
  }
  __syncthreads();
#pragma unroll
  for (int it = 0; it < 16; ++it) {
    int e = it * 256 + t;
    int n = e >> 6, cl = e & 63;
    fsb[((size_t)(b * 256 + nt * 64 + n)) * 512 + ct * 64 + cl] = tile[cl][n];
  }
}

// --------------------------- K5: both projection GEMMs ---------------------
__global__ __launch_bounds__(256) void k_proj_both(
    const unsigned short* __restrict__ At, const unsigned short* __restrict__ Wtt,
    const unsigned short* __restrict__ Asrc, const unsigned short* __restrict__ Wts,
    float* __restrict__ outt, float* __restrict__ outs) {
  __shared__ __align__(16) unsigned short Al[128 * 64];
  __shared__ __align__(16) unsigned short Bl[128 * 64];
  int g = blockIdx.x;
  const unsigned short* A;
  const unsigned short* Wt;
  float* outp;
  int K, bid;
  if (g < 64) { A = At; Wt = Wtt; outp = outt; K = 1024; bid = g; }
  else        { A = Asrc; Wt = Wts; outp = outs; K = 512; bid = g - 64; }
  int nt = bid & 1, mt = bid >> 1;
  int m0 = mt * 128, n0 = nt * 128;
  int t = threadIdx.x, wid = t >> 6, lane = t & 63;
  int wm = wid & 1, wn = wid >> 1;
  int quad = lane >> 4, l15 = lane & 15;

  f32x4 acc[4][4];
  const f32x4 fz = {0.f, 0.f, 0.f, 0.f};
#pragma unroll
  for (int i = 0; i < 4; ++i)
#pragma unroll
    for (int j = 0; j < 4; ++j) acc[i][j] = fz;

  int row4[4];
#pragma unroll
  for (int jj = 0; jj < 4; ++jj) row4[jj] = (wid * 4 + jj) * 8 + (lane >> 3);
  int kcol = (lane & 7) * 8;

  int nkb = K >> 6;
  for (int kb = 0; kb < nkb; ++kb) {
#pragma unroll
    for (int jj = 0; jj < 4; ++jj) {
      gld16(A + (size_t)(m0 + row4[jj]) * K + kb * 64 + kcol,
            (char*)Al + (wid * 4 + jj) * 1024);
      gld16(Wt + (size_t)(n0 + row4[jj]) * K + kb * 64 + kcol,
            (char*)Bl + (wid * 4 + jj) * 1024);
    }
    __syncthreads();
#pragma unroll
    for (int s = 0; s < 2; ++s) {
      s16x8 af[4], bf[4];
#pragma unroll
      for (int i = 0; i < 4; ++i) {
        af[i] = *(const s16x8*)(const void*)(Al + (wm * 64 + i * 16 + l15) * 64 + s * 32 + quad * 8);
        bf[i] = *(const s16x8*)(const void*)(Bl + (wn * 64 + i * 16 + l15) * 64 + s * 32 + quad * 8);
      }
#pragma unroll
      for (int i = 0; i < 4; ++i)
#pragma unroll
        for (int j = 0; j < 4; ++j)
          acc[i][j] = __builtin_amdgcn_mfma_f32_16x16x32_bf16(af[i], bf[j], acc[i][j], 0, 0, 0);
    }
    __syncthreads();
  }
#pragma unroll
  for (int i = 0; i < 4; ++i)
#pragma unroll
    for (int j = 0; j < 4; ++j)
#pragma unroll
      for (int r = 0; r < 4; ++r) {
        int m = m0 + wm * 64 + i * 16 + quad * 4 + r;
        int p = n0 + wn * 64 + j * 16 + l15;
        outp[(size_t)m * 256 + p] = acc[i][j][r];
      }
}

// --------- K5b: fused teacher+student LN/l2norm + pos + gafd ---------------
__global__ void k_ln_both(const float* __restrict__ projt, const float* __restrict__ tb,
                          const float* __restrict__ tg, const float* __restrict__ tbe,
                          const float* __restrict__ projs, const float* __restrict__ sb,
                          const float* __restrict__ sg, const float* __restrict__ sbe,
                          unsigned short* __restrict__ outb,
                          float* __restrict__ pos, float* __restrict__ gsum) {
  __shared__ float l4[4];
  int row = blockIdx.x, t = threadIdx.x;
  // teacher
  float xt = projt[(size_t)row * 256 + t] + tb[t];
  float s1t = block_sum(xt, l4);
  float dt = xt - s1t * (1.f / 256.f);
  float s2t = block_sum(dt * dt, l4);
  float xnt = dt * rsqrtf(s2t * (1.f / 256.f) + 1e-5f) * tg[t] + tbe[t];
  float sst = block_sum(xnt * xnt, l4);
  float ot = xnt / fmaxf(sqrtf(sst), 1e-12f);
  // student
  float xs = projs[(size_t)row * 256 + t] + sb[t];
  float s1s = block_sum(xs, l4);
  float ds = xs - s1s * (1.f / 256.f);
  float s2s = block_sum(ds * ds, l4);
  float xns = ds * rsqrtf(s2s * (1.f / 256.f) + 1e-5f) * sg[t] + sbe[t];
  float sss = block_sum(xns * xns, l4);
  float os = xns / fmaxf(sqrtf(sss), 1e-12f);
  outb[(size_t)row * 256 + t] = f2bf(os);
  float sdot = block_sum(os * ot, l4);
  if (t == 0) pos[row] = sdot * 10.f;  // / TAU
  float dd = os - ot;
  float ssq = block_sum(dd * dd, l4);
  if (t == 0) atomicAdd(gsum, ssq);
}

// --------------------------- K7: neg matrix + masked LSE -------------------
// 128 blocks (8 n-tiles of 32 rows per batch) for 2x CU fill.
__global__ __launch_bounds__(256) void k_abcd_rows(
    const unsigned short* __restrict__ fsnb, const int* __restrict__ bd,
    const float* __restrict__ pos, float* __restrict__ rowloss) {
  __shared__ __align__(16) unsigned short Ab[32 * 64];
  __shared__ __align__(16) unsigned short Bb[256 * 64];
  __shared__ float mrg[32][4][2];
  int b = blockIdx.x >> 3, nb = blockIdx.x & 7;
  int n0 = nb * 32;
  int t = threadIdx.x, w = t >> 6, lane = t & 63, quad = lane >> 4, l15 = lane & 15;
  f32x4 acc[2][4];
  const f32x4 fz = {0.f, 0.f, 0.f, 0.f};
#pragma unroll
  for (int i = 0; i < 2; ++i)
#pragma unroll
    for (int j = 0; j < 4; ++j) acc[i][j] = fz;
  const unsigned short* fb = fsnb + (size_t)b * 256 * 256;

  for (int kc = 0; kc < 4; ++kc) {
    {
      int r = t >> 3, cc = (t & 7) * 8;
      *(uint4*)(void*)(Ab + r * 64 + cc) =
          *(const uint4*)(const void*)(fb + (size_t)(n0 + r) * 256 + kc * 64 + cc);
    }
#pragma unroll
    for (int it = 0; it < 4; ++it) {
      int m = it * 64 + (t >> 2), cc = (t & 3) * 16;
      const uint4* s = (const uint4*)(const void*)(fb + (size_t)m * 256 + kc * 64 + cc);
      *(uint4*)(void*)(Bb + m * 64 + cc) = s[0];
      *(uint4*)(void*)(Bb + m * 64 + cc + 8) = s[1];
    }
    __syncthreads();
#pragma unroll
    for (int s = 0; s < 2; ++s) {
      s16x8 af[2], bf[4];
#pragma unroll
      for (int i = 0; i < 2; ++i)
        af[i] = *(const s16x8*)(const void*)(Ab + (i * 16 + l15) * 64 + s * 32 + quad * 8);
#pragma unroll
      for (int j = 0; j < 4; ++j)
        bf[j] = *(const s16x8*)(const void*)(Bb + (w * 64 + j * 16 + l15) * 64 + s * 32 + quad * 8);
#pragma unroll
      for (int i = 0; i < 2; ++i)
#pragma unroll
        for (int j = 0; j < 4; ++j)
          acc[i][j] = __builtin_amdgcn_mfma_f32_16x16x32_bf16(af[i], bf[j], acc[i][j], 0, 0, 0);
    }
    __syncthreads();
  }

  int nbmask[4];
#pragma unroll
  for (int j = 0; j < 4; ++j) nbmask[j] = bd[b * 256 + w * 64 + j * 16 + l15];
#pragma unroll
  for (int i = 0; i < 2; ++i) {
#pragma unroll
    for (int r = 0; r < 4; ++r) {
      float mxv = -1e30f, se = 0.f;
#pragma unroll
      for (int j = 0; j < 4; ++j) {
        float v = nbmask[j] ? -1e30f : (acc[i][j][r] / 0.1f);
        if (v > mxv) {
          se = se * expf(mxv - v) + 1.f;
          mxv = v;
        } else {
          se += expf(v - mxv);
        }
      }
#pragma unroll
      for (int msk = 1; msk < 16; msk <<= 1) {
        float omx = __shfl_xor(mxv, msk, 64);
        float ose = __shfl_xor(se, msk, 64);
        float nm = fmaxf(mxv, omx);
        se = se * expf(mxv - nm) + ose * expf(omx - nm);
        mxv = nm;
      }
      if (l15 == 0) {
        mrg[i * 16 + quad * 4 + r][w][0] = mxv;
        mrg[i * 16 + quad * 4 + r][w][1] = se;
      }
    }
  }
  __syncthreads();
  if (t < 32) {
    float MX = -1e30f, SE = 0.f;
    for (int ww = 0; ww < 4; ++ww) {
      float omx = mrg[t][ww][0], ose = mrg[t][ww][1];
      float nm = fmaxf(MX, omx);
      SE = SE * expf(MX - nm) + ose * expf(omx - nm);
      MX = nm;
    }
    float p = pos[b * 256 + n0 + t];
    float nm = fmaxf(MX, p);
    float se2 = SE * expf(MX - nm) + expf(p - nm);
    rowloss[b * 256 + n0 + t] = nm + logf(se2) - p;
  }
}

// --------------------------- K8: final scalars -----------------------------
__global__ void k_final(const float* __restrict__ gsum, const float* __restrict__ rowloss,
                        const int* __restrict__ bd, const int* __restrict__ cnt,
                        const int* __restrict__ nbc, float* __restrict__ out) {
  __shared__ float l4[4];
  int t = threadIdx.x;
  float abcd_acc = 0.f, vnum = 0.f;
  for (int b = 0; b < 16; ++b) {
    float c = bd[b * 256 + t] ? rowloss[b * 256 + t] : 0.f;
    float s = block_sum(c, l4);
    if (t == 0) {
      float cb = (float)cnt[b];
      float per = s / fmaxf(cb, 1.f);
      if (cnt[b] > 0 && nbc[b] > 0) {
        abcd_acc += per;
        vnum += 1.f;
      }
    }
  }
  if (t == 0) {
    float gafd = gsum[0] / 1048576.f;
    float abcd = vnum > 0.f ? abcd_acc / fmaxf(vnum, 1.f) : 0.f;
    out[0] = gafd + 0.5f * abcd;
    out[1] = gafd;
    out[2] = abcd;
  }
}

// --------------------------- workspace layout ------------------------------
static constexpr size_t OFF_TPAD = 0;
static constexpr size_t TPAD_BYTES = (size_t)16 * 66 * 66 * 1024 * 2;
static constexpr size_t OFF_WT = OFF_TPAD + TPAD_BYTES;
static constexpr size_t WT_BYTES = (size_t)9 * 16 * 512 * 64 * 2;
static constexpr size_t OFF_HEAT = OFF_WT + WT_BYTES;
static constexpr size_t OFF_GSUM = OFF_HEAT + 262144;
static constexpr size_t OFF_IDX = OFF_GSUM + 256;
static constexpr size_t OFF_FTB = OFF_IDX + 16384;
static constexpr size_t OFF_FSB = OFF_FTB + (size_t)4096 * 1024 * 2;
static constexpr size_t OFF_FSBT = OFF_FSB + (size_t)4096 * 512 * 2;
static constexpr size_t OFF_WTT = OFF_FSBT + (size_t)4096 * 512 * 2;
static constexpr size_t OFF_WTS = OFF_WTT + (size_t)256 * 1024 * 2;
static constexpr size_t OFF_PRT = OFF_WTS + (size_t)256 * 512 * 2;
static constexpr size_t OFF_PRS = OFF_PRT + (size_t)4096 * 256 * 4;
static constexpr size_t OFF_FSNB = OFF_PRS + (size_t)4096 * 256 * 4;
static constexpr size_t OFF_POS = OFF_FSNB + (size_t)4096 * 256 * 2;
static constexpr size_t OFF_BD = OFF_POS + 16384;
static constexpr size_t OFF_CNT = OFF_BD + 16384;
static constexpr size_t OFF_NBC = OFF_CNT + 64;
static constexpr size_t OFF_RL = OFF_NBC + 64;

extern "C" void kernel_launch(void* const* d_in, const int* in_sizes, int n_in,
                              void* d_out, int out_size, void* d_ws, size_t ws_size,
                              hipStream_t stream) {
  const float* teacher = (const float*)d_in[0];
  const float* student = (const float*)d_in[1];
  const float* w1 = (const float*)d_in[2];
  const float* b1 = (const float*)d_in[3];
  const float* w2 = (const float*)d_in[4];
  const float* b2 = (const float*)d_in[5];
  const float* t_w = (const float*)d_in[6];
  const float* t_b = (const float*)d_in[7];
  const float* t_g = (const float*)d_in[8];
  const float* t_be = (const float*)d_in[9];
  const float* s_w = (const float*)d_in[10];
  const float* s_b = (const float*)d_in[11];
  const float* s_g = (const float*)d_in[12];
  const float* s_be = (const float*)d_in[13];
  float* out = (float*)d_out;

  char* ws = (char*)d_ws;
  unsigned short* tpad = (unsigned short*)(ws + OFF_TPAD);
  unsigned short* wt = (unsigned short*)(ws + OFF_WT);
  float* heat = (float*)(ws + OFF_HEAT);
  float* gsum = (float*)(ws + OFF_GSUM);
  int* idx_sel = (int*)(ws + OFF_IDX);
  unsigned short* ftb = (unsigned short*)(ws + OFF_FTB);
  unsigned short* fsb = (unsigned short*)(ws + OFF_FSB);
  unsigned short* fsbT = (unsigned short*)(ws + OFF_FSBT);
  unsigned short* wTt = (unsigned short*)(ws + OFF_WTT);
  unsigned short* wTs = (unsigned short*)(ws + OFF_WTS);
  float* projt = (float*)(ws + OFF_PRT);
  float* projs = (float*)(ws + OFF_PRS);
  unsigned short* fsnb = (unsigned short*)(ws + OFF_FSNB);
  float* pos = (float*)(ws + OFF_POS);
  int* bd = (int*)(ws + OFF_BD);
  int* cnt = (int*)(ws + OFF_CNT);
  int* nbc = (int*)(ws + OFF_NBC);
  float* rowloss = (float*)(ws + OFF_RL);

  hipMemsetAsync(ws + OFF_HEAT, 0, 262144 + 256, stream);  // heat + gsum

  k_pad_wprep<<<18432, 256, 0, stream>>>(teacher, tpad, w1, wt, t_w, wTt, s_w, wTs);
  k_conv<<<512, 512, 0, stream>>>(tpad, wt, b1, w2, heat);
  k_score_topk_sal<<<16, 256, 0, stream>>>(heat, b2, out + 3, idx_sel, bd, cnt, nbc);
  k_gather_t<<<2048, 256, 0, stream>>>(tpad, idx_sel, ftb);
  k_gather_s<<<8192, 256, 0, stream>>>(student, idx_sel, fsbT);
  k_fsb_tr<<<512, 256, 0, stream>>>(fsbT, fsb);
  k_proj_both<<<128, 256, 0, stream>>>(ftb, wTt, fsb, wTs, projt, projs);
  k_ln_both<<<4096, 256, 0, stream>>>(projt, t_b, t_g, t_be, projs, s_b, s_g, s_be,
                                      fsnb, pos, gsum);
  k_abcd_rows<<<128, 256, 0, stream>>>(fsnb, bd, pos, rowloss);
  k_final<<<1, 256, 0, stream>>>(gsum, rowloss, bd, cnt, nbc, out);
}